// Round 1
// baseline (90.035 us; speedup 1.0000x reference)
//
#include <hip/hip_runtime.h>

// FingerprintPool: B=64, A=32, C=64, SEG_LENS=(1,167,512), F_fp=679.
// Math reduction (biases cancel in both softmaxes):
//   d_i[b,a] = x[b,a]·w_inner[i]; e_i[b,a] = x[b,a]·w_inter[i]
//   attn(l): softmax of d_i over hit set of column l
//   sc2[b,l] = sum_a attn*e  (NEG if column empty)
//   a2: softmax of sc2 over l within segment
//   out[b,c] = sum_a x[b,a,c] * sum_i ed_i[a]*H_i[a],
//     H_i[a] = sum_{l in seg i, hit(l,a)} a2[l]/Z_l,  ed = exp(d - dmax), Z_l = sum_hit ed.

constexpr int NB   = 64;
constexpr int NA   = 32;
constexpr int NC   = 64;
constexpr int NFP  = 679;   // fp columns (without the implicit ones column)
constexpr int LTOT = 680;   // 1 + 167 + 512
constexpr int S1   = 1;     // seg1 start
constexpr int S2   = 168;   // seg2 start

__global__ __launch_bounds__(256) void fpool_kernel(
    const float* __restrict__ x,        // (2048, 64)
    const int*   __restrict__ fp,       // (2048, 679)
    const float* __restrict__ w_inner,  // (3, 64)
    const float* __restrict__ w_inter,  // (3, 64)
    float*       __restrict__ out)      // (64, 64)
{
    __shared__ float    x_s[NA][NC + 1];   // +1 pad: bank-conflict-free row reads
    __shared__ float    d_s[6][NA];        // [0..2]=d_i, [3..5]=e_i
    __shared__ float    dmax_s[3];
    __shared__ float    ed_s[3][NA];       // exp(d - dmax)
    __shared__ float    fe_s[3][NA];       // ed * e
    __shared__ unsigned mask_s[LTOT];
    __shared__ float    Z_s[LTOT];
    __shared__ float    sc2_s[LTOT];
    __shared__ float    coef_s[LTOT];      // a2[l] / Z_l (0 for empty columns)
    __shared__ float    H_s[3][NA];
    __shared__ float    Gsum_s[NA];

    const int tid = threadIdx.x;
    const int b   = blockIdx.x;

    // ---- load x tile, zero H ----
    const float* xb = x + (size_t)b * NA * NC;
    for (int idx = tid; idx < NA * NC; idx += 256) {
        x_s[idx >> 6][idx & 63] = xb[idx];
    }
    if (tid < 96) ((float*)H_s)[tid] = 0.f;
    __syncthreads();

    // ---- phase 1: d_i[a], e_i[a] (192 dots of length 64) ----
    if (tid < 192) {
        const int j = tid >> 5, a = tid & 31;
        const float* w = (j < 3) ? (w_inner + j * NC) : (w_inter + (j - 3) * NC);
        float acc = 0.f;
        #pragma unroll
        for (int c = 0; c < NC; ++c) acc += x_s[a][c] * w[c];
        d_s[j][a] = acc;
    }
    __syncthreads();
    if (tid < 3) {
        float m = -3e38f;
        for (int a = 0; a < NA; ++a) m = fmaxf(m, d_s[tid][a]);
        dmax_s[tid] = m;
    }
    __syncthreads();
    if (tid < 96) {
        const int i = tid >> 5, a = tid & 31;
        const float ed = __expf(d_s[i][a] - dmax_s[i]);
        ed_s[i][a] = ed;
        fe_s[i][a] = ed * d_s[3 + i][a];
    }
    __syncthreads();

    // ---- phase 3: per-column hitmask, Z, sc2 ----
    for (int l = tid; l < LTOT; l += 256) {
        unsigned m;
        int i;
        if (l == 0) {
            m = 0xFFFFFFFFu; i = 0;
        } else {
            i = (l >= S2) ? 2 : 1;
            const int* f = fp + (size_t)b * NA * NFP + (l - 1);
            m = 0u;
            #pragma unroll
            for (int a = 0; a < NA; ++a)
                m |= (f[(size_t)a * NFP] != 0) ? (1u << a) : 0u;
        }
        float Z = 0.f, P = 0.f;
        #pragma unroll
        for (int a = 0; a < NA; ++a) {
            const float bit = (float)((m >> a) & 1u);
            Z += bit * ed_s[i][a];
            P += bit * fe_s[i][a];
        }
        mask_s[l] = m;
        Z_s[l]    = Z;
        sc2_s[l]  = m ? (P / Z) : -1e30f;
    }
    __syncthreads();

    // ---- phase 4: softmax over l per segment (1 wave per segment) ----
    {
        const int wave = tid >> 6, lane = tid & 63;
        if (wave < 3) {
            const int s = (wave == 0) ? 0 : (wave == 1 ? S1 : S2);
            const int e = (wave == 0) ? S1 : (wave == 1 ? S2 : LTOT);
            float mx = -3e38f;
            for (int l = s + lane; l < e; l += 64) mx = fmaxf(mx, sc2_s[l]);
            #pragma unroll
            for (int o = 32; o; o >>= 1) mx = fmaxf(mx, __shfl_xor(mx, o));
            float sm = 0.f;
            for (int l = s + lane; l < e; l += 64) sm += __expf(sc2_s[l] - mx);
            #pragma unroll
            for (int o = 32; o; o >>= 1) sm += __shfl_xor(sm, o);
            const float inv = 1.f / sm;
            for (int l = s + lane; l < e; l += 64) {
                const unsigned m = mask_s[l];
                coef_s[l] = m ? (__expf(sc2_s[l] - mx) * inv / Z_s[l]) : 0.f;
            }
        }
    }
    __syncthreads();

    // ---- phase 5: H_i[a] = sum over hit columns of coef ----
    {
        const int a = tid & 31, chunk = tid >> 5;   // 8 chunks of 85 columns
        const int ls = chunk * 85;
        const int le = (ls + 85 < LTOT) ? ls + 85 : LTOT;
        float h0 = 0.f, h1 = 0.f, h2 = 0.f;
        for (int l = ls; l < le; ++l) {
            if ((mask_s[l] >> a) & 1u) {
                const float cf = coef_s[l];
                if (l >= S2)      h2 += cf;
                else if (l >= S1) h1 += cf;
                else              h0 += cf;
            }
        }
        if (h0 != 0.f) atomicAdd(&H_s[0][a], h0);
        if (h1 != 0.f) atomicAdd(&H_s[1][a], h1);
        if (h2 != 0.f) atomicAdd(&H_s[2][a], h2);
    }
    __syncthreads();

    // ---- phase 6: out[b,c] = sum_a x[b,a,c] * sum_i ed_i[a]*H_i[a] ----
    if (tid < NA) {
        Gsum_s[tid] = ed_s[0][tid] * H_s[0][tid]
                    + ed_s[1][tid] * H_s[1][tid]
                    + ed_s[2][tid] * H_s[2][tid];
    }
    __syncthreads();
    if (tid < NC) {
        float acc = 0.f;
        #pragma unroll
        for (int a = 0; a < NA; ++a) acc += Gsum_s[a] * x_s[a][tid];
        out[b * NC + tid] = acc;
    }
}

extern "C" void kernel_launch(void* const* d_in, const int* in_sizes, int n_in,
                              void* d_out, int out_size, void* d_ws, size_t ws_size,
                              hipStream_t stream) {
    const float* x       = (const float*)d_in[0];
    // d_in[1] = batch (unused), d_in[3] = fp_length (unused)
    const int*   fp      = (const int*)d_in[2];
    const float* w_inner = (const float*)d_in[4];
    // d_in[5] = b_inner (cancels in softmax)
    const float* w_inter = (const float*)d_in[6];
    // d_in[7] = b_inter (cancels in softmax)
    float* out = (float*)d_out;

    fpool_kernel<<<NB, 256, 0, stream>>>(x, fp, w_inner, w_inter, out);
}

// Round 2
// 78.630 us; speedup vs baseline: 1.1450x; 1.1450x over previous
//
#include <hip/hip_runtime.h>

// FingerprintPool: B=64, A=32, C=64, SEG_LENS=(1,167,512), F_fp=679.
// Math reduction (biases cancel in both softmaxes):
//   d_i[b,a] = x[b,a]·w_inner[i]; e_i[b,a] = x[b,a]·w_inter[i]
//   attn(l): softmax of d_i over hit set of column l
//   sc2[b,l] = sum_hit ed*e / Z  (excluded if column empty)
//   a2: softmax of sc2 over l within segment
//   out[b,c] = sum_a x[b,a,c] * sum_i ed_i[a]*H_i[a],
//     H_i[a] = sum_{l in seg i, hit(l,a)} a2[l]/Z_l,  ed = exp(d - dmax_i), Z_l = sum_hit ed.

constexpr int NB    = 64;
constexpr int NA    = 32;
constexpr int NC    = 64;
constexpr int NFP   = 679;   // fp columns (without the implicit ones column)
constexpr int LTOT  = 680;   // 1 + 167 + 512
constexpr int S1    = 1;     // seg1 start
constexpr int S2    = 168;   // seg2 start
constexpr int NT    = 1024;  // threads per block (16 waves)
constexpr int NCHK  = 32;    // phase-5 chunks
constexpr int CHKW  = 22;    // ceil(680/32)

__global__ __launch_bounds__(NT) void fpool_kernel(
    const float* __restrict__ x,        // (2048, 64)
    const int*   __restrict__ fp,       // (2048, 679)
    const float* __restrict__ w_inner,  // (3, 64)
    const float* __restrict__ w_inter,  // (3, 64)
    float*       __restrict__ out)      // (64, 64)
{
    __shared__ float    x_s[NA][NC + 1];     // +1 pad: conflict-free both axes
    __shared__ float    ed_s[3][NA];         // exp(d - dmax)
    __shared__ float    fe_s[3][NA];         // ed * e
    __shared__ unsigned mask_s[LTOT];
    __shared__ float    Z_s[LTOT];
    __shared__ float    sc2_s[LTOT];
    __shared__ float    coef_s[LTOT];        // a2[l]/Z_l (0 for empty columns)
    __shared__ float    part_s[NCHK][96];    // phase-5 partials [chunk][i*32+a]
    __shared__ float    H_s[96];             // H_i[a]
    __shared__ float    Gsum_s[NA];

    const int tid = threadIdx.x;
    const int b   = blockIdx.x;
    const int l   = tid;

    // ---- issue fp loads first (latency overlaps the x-tile load) ----
    unsigned m = 0;
    if (l == 0) m = 0xFFFFFFFFu;
    else if (l < LTOT) {
        const int* f = fp + (size_t)b * NA * NFP + (l - 1);
        int v[NA];
        #pragma unroll
        for (int a = 0; a < NA; ++a) v[a] = f[(size_t)a * NFP];
        #pragma unroll
        for (int a = 0; a < NA; ++a) m |= (v[a] != 0) ? (1u << a) : 0u;
    }

    // ---- x tile: 2048 elements, 2 per thread, coalesced ----
    {
        const float* xb = x + (size_t)b * NA * NC;
        int i0 = tid;       x_s[i0 >> 6][i0 & 63] = xb[i0];
        int i1 = tid + NT;  x_s[i1 >> 6][i1 & 63] = xb[i1];
    }
    if (tid < NA) Gsum_s[tid] = 0.f;
    __syncthreads();

    // ---- phase 1+2 fused: d,e dots + group-max + ed/fe (96 threads) ----
    if (tid < 96) {
        const int i = tid >> 5, a = tid & 31;
        const float* wi = w_inner + i * NC;
        const float* wt = w_inter + i * NC;
        float dacc = 0.f, eacc = 0.f;
        #pragma unroll
        for (int c = 0; c < NC; ++c) {
            const float xv = x_s[a][c];
            dacc += xv * wi[c];
            eacc += xv * wt[c];
        }
        // max over the aligned 32-lane group (offsets <32 stay in-group)
        float mx = dacc;
        #pragma unroll
        for (int o = 16; o; o >>= 1) mx = fmaxf(mx, __shfl_xor(mx, o));
        const float ed = __expf(dacc - mx);
        ed_s[i][a] = ed;
        fe_s[i][a] = ed * eacc;
    }
    __syncthreads();

    // ---- phase 3: per-column Z, sc2 from register mask ----
    if (l < LTOT) {
        const int i = (l >= S2) ? 2 : ((l >= S1) ? 1 : 0);
        float Z = 0.f, P = 0.f;
        #pragma unroll
        for (int a = 0; a < NA; ++a) {
            const float bit = (float)((m >> a) & 1u);
            Z += bit * ed_s[i][a];
            P += bit * fe_s[i][a];
        }
        mask_s[l] = m;
        Z_s[l]    = Z;
        sc2_s[l]  = m ? (P / Z) : -1e30f;
    }
    __syncthreads();

    // ---- phase 4: softmax over l per segment (3 waves) ----
    {
        const int wave = tid >> 6, lane = tid & 63;
        if (wave < 3) {
            const int s = (wave == 0) ? 0 : (wave == 1 ? S1 : S2);
            const int e = (wave == 0) ? S1 : (wave == 1 ? S2 : LTOT);
            float mx = -3e38f;
            for (int ll = s + lane; ll < e; ll += 64) mx = fmaxf(mx, sc2_s[ll]);
            #pragma unroll
            for (int o = 32; o; o >>= 1) mx = fmaxf(mx, __shfl_xor(mx, o));
            float sm = 0.f;
            for (int ll = s + lane; ll < e; ll += 64) sm += __expf(sc2_s[ll] - mx);
            #pragma unroll
            for (int o = 32; o; o >>= 1) sm += __shfl_xor(sm, o);
            const float inv = 1.f / sm;
            for (int ll = s + lane; ll < e; ll += 64) {
                const unsigned mm = mask_s[ll];
                coef_s[ll] = mm ? (__expf(sc2_s[ll] - mx) * inv / Z_s[ll]) : 0.f;
            }
        }
    }
    __syncthreads();

    // ---- phase 5: H_i[a] partials, 32 chunks x (3x32) ----
    {
        const int a = tid & 31, chunk = tid >> 5;   // chunk in [0,32)
        const int ls = chunk * CHKW;
        const int le = (ls + CHKW < LTOT) ? ls + CHKW : LTOT;
        float h0 = 0.f, h1 = 0.f, h2 = 0.f;
        for (int ll = ls; ll < le; ++ll) {
            const float cf = coef_s[ll] * (float)((mask_s[ll] >> a) & 1u);
            if (ll >= S2)      h2 += cf;
            else if (ll >= S1) h1 += cf;
            else               h0 += cf;
        }
        part_s[chunk][a]      = h0;
        part_s[chunk][32 + a] = h1;
        part_s[chunk][64 + a] = h2;
    }
    __syncthreads();

    // ---- phase 5b: reduce partials, fold into Gsum ----
    if (tid < 96) {
        float s = 0.f;
        #pragma unroll
        for (int c = 0; c < NCHK; ++c) s += part_s[c][tid];
        H_s[tid] = s;
        const int i = tid >> 5, a = tid & 31;
        atomicAdd(&Gsum_s[a], ed_s[i][a] * s);
    }
    __syncthreads();

    // ---- phase 6: out[b,c] = sum_a Gsum[a] * x[b,a,c] ----
    if (tid < NC) {
        float acc = 0.f;
        #pragma unroll
        for (int a = 0; a < NA; ++a) acc += Gsum_s[a] * x_s[a][tid];
        out[b * NC + tid] = acc;
    }
}

extern "C" void kernel_launch(void* const* d_in, const int* in_sizes, int n_in,
                              void* d_out, int out_size, void* d_ws, size_t ws_size,
                              hipStream_t stream) {
    const float* x       = (const float*)d_in[0];
    // d_in[1] = batch (unused), d_in[3] = fp_length (unused)
    const int*   fp      = (const int*)d_in[2];
    const float* w_inner = (const float*)d_in[4];
    // d_in[5] = b_inner (cancels in softmax)
    const float* w_inter = (const float*)d_in[6];
    // d_in[7] = b_inter (cancels in softmax)
    float* out = (float*)d_out;

    fpool_kernel<<<NB, NT, 0, stream>>>(x, fp, w_inner, w_inter, out);
}